// Round 1
// baseline (279.774 us; speedup 1.0000x reference)
//
#include <hip/hip_runtime.h>
#include <climits>

// Problem constants
#define B_N 64
#define C_N 256
#define M_N 1024
#define P_N 512
#define D_N 16
// words per pattern: 512 bits / 64 = 8 u64
#define WPP 8

// One block per neuron c. 1024 threads = 16 waves.
// Phase 1: pack pattern_logits (c,:,:) sign bits into LDS (64KB) via ballot.
// Phase 2: pack bits (:,c,:) into LDS (4KB).
// Phase 3: each wave handles 4 batch rows; lanes split the 1024 entries;
//          Hamming via u64 xor+popcount; argmin key=(d<<10)|m gives
//          first-index tie-break; gather value_logits > 0.
__global__ __launch_bounds__(1024) void vgram_kernel(
    const float* __restrict__ bits,   // (B, C, P)
    const float* __restrict__ plog,   // (C, M, P)
    const float* __restrict__ vlog,   // (C, M, D)
    float* __restrict__ out)          // (B, C, D)
{
    // pattern LDS: 4 planes of [m*2 + (j&1)]; plane k holds words j=2k,2k+1
    __shared__ __align__(16) unsigned long long pat_lds[4 * 2048];  // 64 KB
    __shared__ unsigned long long bits_lds[B_N * WPP];              // 4 KB

    const int c    = blockIdx.x;
    const int tid  = threadIdx.x;
    const int lane = tid & 63;
    const int wid  = tid >> 6;   // 0..15

    // ---------------- Phase 1: stage patterns ----------------
    // 8192 u64 words total; word w: m = w>>3, j = w&7; floats at
    // plog[c*524288 + w*64 + lane]  (perfectly sequential reads)
    const float* pc = plog + (size_t)c * (M_N * P_N);
    for (int r = 0; r < 8; ++r) {
        const int wbase = wid * 512 + r * 64;
        unsigned long long held = 0ull;
        #pragma unroll
        for (int t = 0; t < 64; ++t) {
            const int w = wbase + t;
            const float f = pc[(size_t)w * 64 + lane];
            const unsigned long long bal = __ballot(f > 0.0f);
            held = (lane == t) ? bal : held;
        }
        const int w = wbase + lane;
        const int m = w >> 3;
        const int j = w & 7;
        pat_lds[((j >> 1) << 11) + m * 2 + (j & 1)] = held;
    }

    // ---------------- Phase 2: stage bits ----------------
    // 512 u64 words; word v: b = v>>3, j = v&7
    for (int t = 0; t < 32; ++t) {
        const int v = wid * 32 + t;
        const int b = v >> 3;
        const int j = v & 7;
        const float f = bits[((size_t)b * C_N + c) * P_N + j * 64 + lane];
        const unsigned long long bal = __ballot(f > 0.0f);
        if (lane == 0) bits_lds[v] = bal;
    }
    __syncthreads();

    // ---------------- Phase 3: distances + argmin ----------------
    const int bbase = wid * 4;   // 16 waves x 4 = 64 batch rows

    unsigned long long bw[4][WPP];
    #pragma unroll
    for (int bb = 0; bb < 4; ++bb)
        #pragma unroll
        for (int j = 0; j < WPP; ++j)
            bw[bb][j] = bits_lds[(bbase + bb) * WPP + j];

    int key[4] = {INT_MAX, INT_MAX, INT_MAX, INT_MAX};

    for (int mm = 0; mm < 16; ++mm) {
        const int m = mm * 64 + lane;
        unsigned long long pw[WPP];
        #pragma unroll
        for (int k = 0; k < 4; ++k) {
            const ulonglong2 v =
                *reinterpret_cast<const ulonglong2*>(&pat_lds[(k << 11) + m * 2]);
            pw[2 * k]     = v.x;
            pw[2 * k + 1] = v.y;
        }
        #pragma unroll
        for (int bb = 0; bb < 4; ++bb) {
            int d = 0;
            #pragma unroll
            for (int j = 0; j < WPP; ++j)
                d += __popcll(pw[j] ^ bw[bb][j]);
            const int k2 = (d << 10) | m;
            key[bb] = min(key[bb], k2);
        }
    }

    // wave-wide min reduce per batch row; then gather+threshold values
    #pragma unroll
    for (int bb = 0; bb < 4; ++bb) {
        int k2 = key[bb];
        #pragma unroll
        for (int off = 32; off; off >>= 1)
            k2 = min(k2, __shfl_xor(k2, off));
        const int idx = k2 & 1023;
        const int b = bbase + bb;
        if (lane < D_N) {
            const float v = vlog[((size_t)c * M_N + idx) * D_N + lane];
            out[((size_t)b * C_N + c) * D_N + lane] = (v > 0.0f) ? 1.0f : 0.0f;
        }
    }
}

extern "C" void kernel_launch(void* const* d_in, const int* in_sizes, int n_in,
                              void* d_out, int out_size, void* d_ws, size_t ws_size,
                              hipStream_t stream) {
    const float* bits = (const float*)d_in[0];   // (64, 256, 512)
    const float* plog = (const float*)d_in[1];   // (256, 1024, 512)
    const float* vlog = (const float*)d_in[2];   // (256, 1024, 16)
    float* out = (float*)d_out;                  // (64, 256, 16)

    vgram_kernel<<<C_N, 1024, 0, stream>>>(bits, plog, vlog, out);
}

// Round 2
// 124.165 us; speedup vs baseline: 2.2532x; 2.2532x over previous
//
#include <hip/hip_runtime.h>
#include <climits>

// Problem constants
#define B_N 64
#define C_N 256
#define M_N 1024
#define P_N 512
#define D_N 16
#define WPP 8   // 8 u64 words per 512-bit pattern

// Bit-order permutation (applied identically to patterns and query bits, so
// Hamming distances are unchanged): word j of entry m packs positions
//   p_local = (j>>2)*256 + 4*lane + (j&3)
// which falls out of float4 loads + 4 ballots per load.
//
// One block per neuron c, 1024 threads = 16 waves, 1 block/CU.
// Phase A: pack query bits (4 batch rows per wave, 2 float4 loads + 8 ballots).
// Phase B: pack pattern sign bits with 2-deep register double-buffered float4
//          loads (4 KB/wave always in flight) + 16 ballots per 1024 floats.
// Phase C: Hamming argmin (key=(d<<10)|m for exact first-index tie-break),
//          gather value_logits > 0.

#define PLOAD(A0, A1, A2, A3, i)                                   \
  {                                                                \
    const float4* s_ = (const float4*)(pc + (size_t)(i) * 1024);   \
    A0 = s_[lane];                                                 \
    A1 = s_[64 + lane];                                            \
    A2 = s_[128 + lane];                                           \
    A3 = s_[192 + lane];                                           \
  }

#define PPROC(A0, A1, A2, A3, i)                                              \
  {                                                                           \
    unsigned long long held_ = 0, bal_;                                       \
    bal_ = __ballot(A0.x > 0.0f); if (lane == 0)  held_ = bal_;               \
    bal_ = __ballot(A0.y > 0.0f); if (lane == 1)  held_ = bal_;               \
    bal_ = __ballot(A0.z > 0.0f); if (lane == 2)  held_ = bal_;               \
    bal_ = __ballot(A0.w > 0.0f); if (lane == 3)  held_ = bal_;               \
    bal_ = __ballot(A1.x > 0.0f); if (lane == 4)  held_ = bal_;               \
    bal_ = __ballot(A1.y > 0.0f); if (lane == 5)  held_ = bal_;               \
    bal_ = __ballot(A1.z > 0.0f); if (lane == 6)  held_ = bal_;               \
    bal_ = __ballot(A1.w > 0.0f); if (lane == 7)  held_ = bal_;               \
    bal_ = __ballot(A2.x > 0.0f); if (lane == 8)  held_ = bal_;               \
    bal_ = __ballot(A2.y > 0.0f); if (lane == 9)  held_ = bal_;               \
    bal_ = __ballot(A2.z > 0.0f); if (lane == 10) held_ = bal_;               \
    bal_ = __ballot(A2.w > 0.0f); if (lane == 11) held_ = bal_;               \
    bal_ = __ballot(A3.x > 0.0f); if (lane == 12) held_ = bal_;               \
    bal_ = __ballot(A3.y > 0.0f); if (lane == 13) held_ = bal_;               \
    bal_ = __ballot(A3.z > 0.0f); if (lane == 14) held_ = bal_;               \
    bal_ = __ballot(A3.w > 0.0f); if (lane == 15) held_ = bal_;               \
    if (lane < 16) {                                                          \
      const int W_ = wid * 512 + (i) * 16 + lane;                             \
      const int m_ = W_ >> 3;                                                 \
      const int j_ = W_ & 7;                                                  \
      pat_lds[((j_ >> 1) << 11) + m_ * 2 + (j_ & 1)] = held_;                 \
    }                                                                         \
  }

__global__ __launch_bounds__(1024) void vgram_kernel(
    const float* __restrict__ bits,   // (B, C, P)
    const float* __restrict__ plog,   // (C, M, P)
    const float* __restrict__ vlog,   // (C, M, D)
    float* __restrict__ out)          // (B, C, D)
{
    // pattern LDS: plane k (k=0..3) holds words j=2k,2k+1: [k*2048 + m*2 + (j&1)]
    __shared__ __align__(16) unsigned long long pat_lds[4 * 2048];  // 64 KB
    __shared__ unsigned long long bits_lds[B_N * WPP];              // 4 KB

    const int c    = blockIdx.x;
    const int tid  = threadIdx.x;
    const int lane = tid & 63;
    const int wid  = tid >> 6;   // 0..15

    // ---------------- Phase A: pack query bits (same permutation) ----------
    {
        const int b0 = wid * 4;
        #pragma unroll
        for (int bb = 0; bb < 4; ++bb) {
            const int b = b0 + bb;
            const float4* src = (const float4*)(bits + ((size_t)b * C_N + c) * P_N);
            const float4 f0 = src[lane];        // q=0: positions 4*lane+k
            const float4 f1 = src[64 + lane];   // q=1: positions 256+4*lane+k
            unsigned long long held = 0, bal;
            bal = __ballot(f0.x > 0.0f); if (lane == 0) held = bal;
            bal = __ballot(f0.y > 0.0f); if (lane == 1) held = bal;
            bal = __ballot(f0.z > 0.0f); if (lane == 2) held = bal;
            bal = __ballot(f0.w > 0.0f); if (lane == 3) held = bal;
            bal = __ballot(f1.x > 0.0f); if (lane == 4) held = bal;
            bal = __ballot(f1.y > 0.0f); if (lane == 5) held = bal;
            bal = __ballot(f1.z > 0.0f); if (lane == 6) held = bal;
            bal = __ballot(f1.w > 0.0f); if (lane == 7) held = bal;
            if (lane < 8) bits_lds[b * WPP + lane] = held;
        }
    }

    // ---------------- Phase B: pack patterns, double-buffered --------------
    // Wave wid owns words [wid*512, wid*512+512) = floats [wid*32768, +32768).
    const float* pc = plog + (size_t)c * (M_N * P_N) + (size_t)wid * 32768;

    {
        float4 a0, a1, a2, a3, b0, b1, b2, b3;
        PLOAD(a0, a1, a2, a3, 0);
        #pragma unroll 1
        for (int i = 0; i < 30; i += 2) {
            PLOAD(b0, b1, b2, b3, i + 1);
            PPROC(a0, a1, a2, a3, i);
            PLOAD(a0, a1, a2, a3, i + 2);
            PPROC(b0, b1, b2, b3, i + 1);
        }
        PLOAD(b0, b1, b2, b3, 31);
        PPROC(a0, a1, a2, a3, 30);
        PPROC(b0, b1, b2, b3, 31);
    }
    __syncthreads();

    // ---------------- Phase C: distances + argmin --------------------------
    const int bbase = wid * 4;   // 16 waves x 4 = 64 batch rows

    unsigned long long bw[4][WPP];
    #pragma unroll
    for (int bb = 0; bb < 4; ++bb)
        #pragma unroll
        for (int j = 0; j < WPP; ++j)
            bw[bb][j] = bits_lds[(bbase + bb) * WPP + j];

    int key[4] = {INT_MAX, INT_MAX, INT_MAX, INT_MAX};

    for (int mm = 0; mm < 16; ++mm) {
        const int m = mm * 64 + lane;
        unsigned long long pw[WPP];
        #pragma unroll
        for (int k = 0; k < 4; ++k) {
            const ulonglong2 v =
                *reinterpret_cast<const ulonglong2*>(&pat_lds[(k << 11) + m * 2]);
            pw[2 * k]     = v.x;
            pw[2 * k + 1] = v.y;
        }
        #pragma unroll
        for (int bb = 0; bb < 4; ++bb) {
            int d = 0;
            #pragma unroll
            for (int j = 0; j < WPP; ++j)
                d += __popcll(pw[j] ^ bw[bb][j]);
            const int k2 = (d << 10) | m;
            key[bb] = min(key[bb], k2);
        }
    }

    // wave-wide min reduce per batch row; then gather+threshold values
    #pragma unroll
    for (int bb = 0; bb < 4; ++bb) {
        int k2 = key[bb];
        #pragma unroll
        for (int off = 32; off; off >>= 1)
            k2 = min(k2, __shfl_xor(k2, off));
        const int idx = k2 & 1023;
        const int b = bbase + bb;
        if (lane < D_N) {
            const float v = vlog[((size_t)c * M_N + idx) * D_N + lane];
            out[((size_t)b * C_N + c) * D_N + lane] = (v > 0.0f) ? 1.0f : 0.0f;
        }
    }
}

extern "C" void kernel_launch(void* const* d_in, const int* in_sizes, int n_in,
                              void* d_out, int out_size, void* d_ws, size_t ws_size,
                              hipStream_t stream) {
    const float* bits = (const float*)d_in[0];   // (64, 256, 512)
    const float* plog = (const float*)d_in[1];   // (256, 1024, 512)
    const float* vlog = (const float*)d_in[2];   // (256, 1024, 16)
    float* out = (float*)d_out;                  // (64, 256, 16)

    vgram_kernel<<<C_N, 1024, 0, stream>>>(bits, plog, vlog, out);
}